// Round 9
// baseline (222.823 us; speedup 1.0000x reference)
//
#include <hip/hip_runtime.h>
#include <stdint.h>

// Problem constants (fixed by the reference setup)
#define B_ 32
#define I_ 16384
#define H_ 1024
#define T_ 10
#define M_ 320   // T_*B_  (GEMM M dimension, m = t*32 + b)
#define NW 64    // GEMM per-block n-tile width (2 blocks/CU)
#define BK 32    // K rows per pipeline stage
#define RB 3     // raw-stage LDS ring depth
#define SCAN_BLOCKS 256   // H_/4

typedef __attribute__((ext_vector_type(8))) short short8;  // 8 bf16 (4 VGPRs)
typedef __attribute__((ext_vector_type(4))) float f32x4;
typedef __attribute__((ext_vector_type(2))) float f32x2;
typedef __attribute__((ext_vector_type(4))) unsigned int u32x4;

// ---------------------------------------------------------------------------
// Kernel 1: pack spikes [B][I][T] f32 -> Sbf [M=T*B][I] bf16 (exact: 0/1)
// ---------------------------------------------------------------------------
__global__ __launch_bounds__(256) void pack_s(const float* __restrict__ spikes,
                                              uint16_t* __restrict__ Sbf) {
  __shared__ __align__(16) uint16_t tile[M_ * 40];  // [m][il], il<32 pad->40
  const int i0 = blockIdx.x * 32;
#pragma unroll
  for (int p = 0; p < 10; p++) {
    int e = p * 256 + threadIdx.x;          // f32x4 index
    int b = e / 80;                          // 80 f32x4 per b-row
    int r = e - b * 80;
    f32x4 val = *(const f32x4*)&spikes[(size_t)b * (I_ * T_) + (size_t)i0 * T_ + r * 4];
#pragma unroll
    for (int j = 0; j < 4; j++) {
      int pos = r * 4 + j;                   // pos = il*10 + t
      int il = pos / 10;
      int t = pos - il * 10;
      float f = (j == 0) ? val.x : (j == 1) ? val.y : (j == 2) ? val.z : val.w;
      union { float f; unsigned int u; } cv; cv.f = f;
      tile[(t * 32 + b) * 40 + il] = (uint16_t)(cv.u >> 16);  // exact for 0/1
    }
  }
  __syncthreads();
#pragma unroll
  for (int p = 0; p < 5; p++) {
    int e = p * 256 + threadIdx.x;
    int m = e >> 2, il8 = e & 3;
    u32x4 w = *(const u32x4*)&tile[m * 40 + il8 * 8];
    *(u32x4*)&Sbf[(size_t)m * I_ + i0 + il8 * 8] = w;
  }
}

// ---------------------------------------------------------------------------
// Kernel 2: GEMM  partial[ks][320][1024] = Sbf * (weight*strength)
// 2-term bf16 split (w = hi + lo); fp32-class accuracy.
//
// ROUND-9: depth experiment via the PROVEN round-3 mechanism (the round-7
// double-reg-set source killed the container twice; this avoids it).
// Structure: raw fp32 W/S tiles stream into an RB=3 LDS ring via
// global_load_lds (no dest regs -> no liveness gating, no spill risk),
// with a CORRECT counted-vmcnt ledger (round 3 had an off-by-one):
//   prologue: issue W0,W1,A0,W2 -> vmcnt(6) [W0 landed] -> barrier ->
//             PACK(0) -> vmcnt(4) [W1 landed] -> lgkm(0) -> barrier
//   iter s:   PACK(s+1) | COMPUTE(s) | ISSUE_A(s+1) | ISSUE_W(s+3) ->
//             vmcnt(4) [W(s+2) landed; A(s+1)+W(s+3) stay in flight]
//             (tail: vmcnt(2)) -> lgkm(0) -> barrier
// Issue-to-wait lead = ONE FULL STAGE PERIOD; 2 W-bursts always in flight.
// Ring safety: ISSUE_W(s+3) writes slot (s+3)%3 = s%3, whose raw data was
// consumed by PACK(s) one barrier earlier.
// Geometry from round 6: NW=64, KS=32, ks-major blocks (XCD-local A),
// 640 thr; loaders = waves 0-7 (wave w stages rows 4w..4w+3; per-lane
// global addr (4w + lane>>4)*H + nbase + (lane&15)*4; LDS dest wave-uniform
// rawW[rb][w*256], HW adds lane*16 -> linear [row][col] layout).
// Packers = tid<256 (col wn=tid&63, row-octet wko): raw reads are 2
// lanes/bank (free); packed writes/reads use the proven 40-ushort rows.
// Value->position mapping identical to rounds 4-6 (ascending k, hi then
// lo) -> bit-identical output.  LDS 68.5 KB -> 2 blocks/CU @ (640,5).
// ---------------------------------------------------------------------------
__global__ __launch_bounds__(640, 5) void gemm(const uint16_t* __restrict__ Sbf,
                                               const float* __restrict__ Wg,
                                               const float* __restrict__ Sg,
                                               float* __restrict__ partial,
                                               int kchunk, int KS) {
  __shared__ __align__(16) float rawW[RB][BK * NW];        // [32][64] f32, 8KB
  __shared__ __align__(16) float rawS[RB][BK * NW];
  __shared__ __align__(16) uint16_t WhiL[2][NW * 40];      // 5.12 KB each
  __shared__ __align__(16) uint16_t WloL[2][NW * 40];

  const int ks = blockIdx.x % KS;      // ks fastest: same-ks blocks same XCD
  const int nt = blockIdx.x / KS;
  const int nbase = nt * NW;
  const int tid = threadIdx.x;
  const int lane = tid & 63, wid = tid >> 6;   // wid 0..9
  const int quad = lane >> 4, l15 = lane & 15;

  const int stages = kchunk >> 5;      // BK = 32 (stages >= 16 for KS<=32)
  const int kofs = ks * kchunk;

  // A-fragment pointers: lane holds A[m][quad*8 + j] -> 16B contiguous global
  const uint16_t* aptr0 = Sbf + (size_t)(wid * 32 + l15) * I_ + quad * 8;
  const uint16_t* aptr1 = aptr0 + (size_t)16 * I_;

  // W staging (waves 0-7): wave w stages rows 4w..4w+3 of the 32x64 tile.
  const size_t gstage = (size_t)(wid * 4 + (lane >> 4)) * H_ + nbase + (lane & 15) * 4;

  // Packers (tid < 256): column wn, 8-row octet wko
  const int wn = tid & 63;
  const int wko = (tid >> 6) & 3;

  f32x4 acc[2][4];
#pragma unroll
  for (int a = 0; a < 2; a++)
#pragma unroll
    for (int b = 0; b < 4; b++) acc[a][b] = f32x4{0.f, 0.f, 0.f, 0.f};

  u32x4 af[2];                         // current-stage A fragments

#define ISSUE_W(sidx)                                                       \
  if (tid < 512) {                                                          \
    const int _rb = (sidx) % RB;                                            \
    const float* gw = Wg + (size_t)(kofs + (sidx) * BK) * H_ + gstage;      \
    const float* gs = Sg + (size_t)(kofs + (sidx) * BK) * H_ + gstage;      \
    __builtin_amdgcn_global_load_lds(                                       \
        (const __attribute__((address_space(1))) void*)gw,                  \
        (__attribute__((address_space(3))) void*)&rawW[_rb][wid * 256],     \
        16, 0, 0);                                                          \
    __builtin_amdgcn_global_load_lds(                                       \
        (const __attribute__((address_space(1))) void*)gs,                  \
        (__attribute__((address_space(3))) void*)&rawS[_rb][wid * 256],     \
        16, 0, 0);                                                          \
  }

#define ISSUE_A(kb)                                                         \
  {                                                                         \
    af[0] = *(const u32x4*)(aptr0 + (kb));                                  \
    af[1] = *(const u32x4*)(aptr1 + (kb));                                  \
  }

  // pack raw[(sidx)%RB] -> hi/lo planes of packed buffer (sidx)&1
#define PACK_W(sidx)                                                        \
  if (tid < 256) {                                                          \
    const int _rb = (sidx) % RB;                                            \
    const int _pn = (sidx) & 1;                                             \
    unsigned int hw[4], lw[4];                                              \
    _Pragma("unroll")                                                       \
    for (int j2 = 0; j2 < 4; j2++) {                                        \
      unsigned int hh[2], ll[2];                                            \
      _Pragma("unroll")                                                     \
      for (int e = 0; e < 2; e++) {                                         \
        int r = wko * 8 + j2 * 2 + e;                                       \
        float p = rawW[_rb][r * 64 + wn] * rawS[_rb][r * 64 + wn];          \
        union { float f; unsigned int u; } cv; cv.f = p;                    \
        unsigned int hb = (cv.u + 0x7FFFu + ((cv.u >> 16) & 1u)) >> 16;     \
        union { unsigned int u; float f; } hv; hv.u = hb << 16;             \
        float lo = p - hv.f;                                                \
        union { float f; unsigned int u; } cl; cl.f = lo;                   \
        unsigned int lb = (cl.u + 0x7FFFu + ((cl.u >> 16) & 1u)) >> 16;     \
        hh[e] = hb; ll[e] = lb;                                             \
      }                                                                     \
      hw[j2] = hh[0] | (hh[1] << 16);                                       \
      lw[j2] = ll[0] | (ll[1] << 16);                                       \
    }                                                                       \
    int wofs = wn * 40 + wko * 8;                                           \
    *(u32x4*)&WhiL[_pn][wofs] = u32x4{hw[0], hw[1], hw[2], hw[3]};          \
    *(u32x4*)&WloL[_pn][wofs] = u32x4{lw[0], lw[1], lw[2], lw[3]};          \
  }

#define COMPUTE(pc)                                                         \
  {                                                                         \
    short8 a0 = __builtin_bit_cast(short8, af[0]);                          \
    short8 a1 = __builtin_bit_cast(short8, af[1]);                          \
    _Pragma("unroll")                                                       \
    for (int tn = 0; tn < 4; ++tn) {                                        \
      int n = tn * 16 + l15;                                                \
      short8 bhi = *(const short8*)&WhiL[pc][n * 40 + quad * 8];            \
      short8 blo = *(const short8*)&WloL[pc][n * 40 + quad * 8];            \
      acc[0][tn] = __builtin_amdgcn_mfma_f32_16x16x32_bf16(a0, bhi, acc[0][tn], 0, 0, 0); \
      acc[0][tn] = __builtin_amdgcn_mfma_f32_16x16x32_bf16(a0, blo, acc[0][tn], 0, 0, 0); \
      acc[1][tn] = __builtin_amdgcn_mfma_f32_16x16x32_bf16(a1, bhi, acc[1][tn], 0, 0, 0); \
      acc[1][tn] = __builtin_amdgcn_mfma_f32_16x16x32_bf16(a1, blo, acc[1][tn], 0, 0, 0); \
    }                                                                       \
  }

  // ---- prologue ----
  ISSUE_W(0);
  ISSUE_W(1);
  ISSUE_A(kofs);
  ISSUE_W(2);
  if (tid < 512) asm volatile("s_waitcnt vmcnt(6)" ::: "memory");  // W0 landed
  __builtin_amdgcn_s_barrier();
  __builtin_amdgcn_sched_barrier(0);
  PACK_W(0);
  if (tid < 512) asm volatile("s_waitcnt vmcnt(4)" ::: "memory");  // W1 landed
  asm volatile("s_waitcnt lgkmcnt(0)" ::: "memory");
  __builtin_amdgcn_s_barrier();
  __builtin_amdgcn_sched_barrier(0);

  // ---- main loop: one barrier per stage; vmcnt never drained to 0 ----
  for (int s = 0; s < stages; ++s) {
    if (s + 1 < stages) PACK_W(s + 1);       // raw (s+1)%RB -> packed (s+1)&1
    __builtin_amdgcn_sched_barrier(0);
    COMPUTE(s & 1);
    __builtin_amdgcn_sched_barrier(0);
    if (s + 1 < stages) {
      ISSUE_A(kofs + (s + 1) * BK);
      if (s + 3 < stages) {
        ISSUE_W(s + 3);                      // slot s%RB (consumed by PACK(s))
        if (tid < 512) asm volatile("s_waitcnt vmcnt(4)" ::: "memory");  // W(s+2)
      } else {
        if (tid < 512) asm volatile("s_waitcnt vmcnt(2)" ::: "memory");  // tail
      }
      asm volatile("s_waitcnt lgkmcnt(0)" ::: "memory");
      __builtin_amdgcn_s_barrier();
      __builtin_amdgcn_sched_barrier(0);
    }
  }

  // ---- epilogue: C/D layout col=lane&15, row=quad*4+reg ----
#pragma unroll
  for (int tm = 0; tm < 2; tm++)
#pragma unroll
    for (int tn = 0; tn < 4; tn++) {
      int mrow = wid * 32 + tm * 16 + quad * 4;
      int ncol = nbase + tn * 16 + l15;
      float* dst = partial + ((size_t)ks * M_ + mrow) * H_ + ncol;
      dst[0 * H_] = acc[tm][tn].x;
      dst[1 * H_] = acc[tm][tn].y;
      dst[2 * H_] = acc[tm][tn].z;
      dst[3 * H_] = acc[tm][tn].w;
    }
#undef PACK_W
#undef ISSUE_W
#undef ISSUE_A
#undef COMPUTE
}

// ---------------------------------------------------------------------------
// Kernel 3: deterministic reduction of K-split partials -> weighted [320][1024]
// Compile-time unroll for KS=32; single accumulator, ascending k order.
// ---------------------------------------------------------------------------
__global__ __launch_bounds__(256) void reduce_w(const float* __restrict__ partial,
                                                float* __restrict__ weighted,
                                                int KS) {
  int j = (blockIdx.x * 256 + threadIdx.x) * 4;
  f32x4 s = f32x4{0.f, 0.f, 0.f, 0.f};
  if (KS == 32) {
#pragma unroll
    for (int k = 0; k < 32; k++) {
      f32x4 p = *(const f32x4*)&partial[(size_t)k * (M_ * H_) + j];
      s += p;
    }
  } else {
    for (int k = 0; k < KS; k++) {
      f32x4 p = *(const f32x4*)&partial[(size_t)k * (M_ * H_) + j];
      s += p;
    }
  }
  *(f32x4*)&weighted[j] = s;
}

// ---------------------------------------------------------------------------
// Kernel 4: LIF scan (round-5 structure).  One thread per (b,h); win[t]
// preloaded to regs; zero atomics; diag via shfl trees + per-block partials.
// ---------------------------------------------------------------------------
__global__ __launch_bounds__(128) void scan(const float* __restrict__ weighted,
                                            const float* __restrict__ threshold,
                                            const float* __restrict__ fre0,
                                            const float* __restrict__ p_tau_mem,
                                            const float* __restrict__ p_tau_syn,
                                            const float* __restrict__ p_target,
                                            const float* __restrict__ p_lr,
                                            float* __restrict__ out,
                                            float* __restrict__ dpart) {
  const int tid = threadIdx.x;
  const int lane = tid & 63;
  const int wv = tid >> 6;             // wave 0..1
  const int b = lane & 31;             // batch (shfl-reduce dimension)
  const int hg = lane >> 5;            // h within wave (0..1)
  const int h = blockIdx.x * 4 + wv * 2 + hg;

  const float alpha_mem = expf(-0.001f / p_tau_mem[0]);
  const float alpha_syn = expf(-0.001f / p_tau_syn[0]);
  const float target = p_target[0], lr = p_lr[0];

  float win[T_];
#pragma unroll
  for (int t = 0; t < T_; t++)
    win[t] = weighted[(size_t)(t * 32 + b) * H_ + h];

  float fre = fre0[h];
  float thr = threshold[h];
  float v = 0.f, isyn = 0.f;
  float spk[T_], dv[T_], dr[T_], dtt[T_];

#pragma unroll
  for (int t = 0; t < T_; t++) {
    isyn = alpha_syn * isyn + win[t];
    v = alpha_mem * v + isyn;
    float spike = (v >= thr) ? 1.f : 0.f;
    v -= spike * thr;
    spk[t] = spike;
    // spike count over the 32 b-lanes of this h (exact integer sum)
    float r = spike;
    r += __shfl_xor(r, 1);
    r += __shfl_xor(r, 2);
    r += __shfl_xor(r, 4);
    r += __shfl_xor(r, 8);
    r += __shfl_xor(r, 16);
    float rate = r * (1.f / 32.f);
    fre = 0.99f * fre + 0.01f * rate;            // identical in 32 lanes
    thr = thr + lr * (fre - target);
    // diagnostics (wave partials, deterministic trees)
    float vv = v;
#pragma unroll
    for (int off = 1; off <= 32; off <<= 1) vv += __shfl_xor(vv, off);
    float r2 = r + __shfl_xor(r, 32);            // counts: h0+h1 (uniform)
    float t2 = thr + __shfl_xor(thr, 32);        // thr: h0+h1 (uniform)
    dv[t] = vv;                                  // sum v over 64 lanes
    dr[t] = r2 * (1.f / 32.f);                   // rate_h0 + rate_h1 (exact)
    dtt[t] = t2;
  }

  // spike output: 10 contiguous floats at out[b*H*T + h*T]
  {
    float* o = out + (size_t)b * (H_ * T_) + (size_t)h * T_;
#pragma unroll
    for (int p = 0; p < 5; p++)
      *(f32x2*)&o[p * 2] = f32x2{spk[p * 2], spk[p * 2 + 1]};
  }

  // block diag partial: combine the 2 waves via LDS, write 30 floats
  __shared__ float dl[2][30];
  if (lane == 0) {
#pragma unroll
    for (int t = 0; t < T_; t++) {
      dl[wv][t] = dv[t];
      dl[wv][10 + t] = dr[t];
      dl[wv][20 + t] = dtt[t];
    }
  }
  __syncthreads();
  if (tid < 30) dpart[(size_t)blockIdx.x * 30 + tid] = dl[0][tid] + dl[1][tid];
}

// ---------------------------------------------------------------------------
// Kernel 5: reduce the 256x30 diag partials -> out[327680..327709].
// ---------------------------------------------------------------------------
__global__ __launch_bounds__(128) void reduce_d(const float* __restrict__ dpart,
                                                float* __restrict__ out) {
  __shared__ float accl[4][32];
  const int s = threadIdx.x >> 5;      // slice 0..3
  const int c = threadIdx.x & 31;      // counter 0..31 (0..29 valid)
  float sum = 0.f;
  if (c < 30) {
    for (int k = s * 64; k < s * 64 + 64; k++)
      sum += dpart[(size_t)k * 30 + c];
  }
  accl[s][c] = sum;
  __syncthreads();
  if (threadIdx.x < 30) {
    float tot = accl[0][threadIdx.x] + accl[1][threadIdx.x] +
                accl[2][threadIdx.x] + accl[3][threadIdx.x];
    float scale = (threadIdx.x < 10) ? (1.f / 32768.f) : (1.f / 1024.f);
    out[327680 + threadIdx.x] = tot * scale;
  }
}

// ---------------------------------------------------------------------------
extern "C" void kernel_launch(void* const* d_in, const int* in_sizes, int n_in,
                              void* d_out, int out_size, void* d_ws, size_t ws_size,
                              hipStream_t stream) {
  const float* spikes    = (const float*)d_in[0];
  const float* weight    = (const float*)d_in[1];
  const float* strength  = (const float*)d_in[2];
  const float* threshold = (const float*)d_in[3];
  const float* fre0      = (const float*)d_in[4];
  const float* tau_mem   = (const float*)d_in[5];
  const float* tau_syn   = (const float*)d_in[6];
  const float* target    = (const float*)d_in[7];
  const float* lr        = (const float*)d_in[8];
  float* out = (float*)d_out;

  const size_t sbf_bytes = (size_t)M_ * I_ * 2;   // 10.5 MB bf16 A-matrix
  const size_t slice     = (size_t)M_ * H_ * 4;   // 1.31 MB per K-split partial
  const size_t wt_bytes  = (size_t)M_ * H_ * 4;   // weighted
  const size_t dp_bytes  = (size_t)SCAN_BLOCKS * 30 * 4;
  int KS = 32;                                    // shrink if ws is small
  while (KS > 1 &&
         sbf_bytes + (size_t)KS * slice + wt_bytes + dp_bytes > ws_size)
    KS >>= 1;

  uint16_t* Sbf   = (uint16_t*)d_ws;
  float* partial  = (float*)((char*)d_ws + sbf_bytes);
  float* weighted = (float*)((char*)d_ws + sbf_bytes + (size_t)KS * slice);
  float* dpart    = (float*)((char*)d_ws + sbf_bytes + (size_t)KS * slice + wt_bytes);

  pack_s<<<I_ / 32, 256, 0, stream>>>(spikes, Sbf);
  gemm<<<(H_ / NW) * KS, 640, 0, stream>>>(Sbf, weight, strength, partial,
                                           I_ / KS, KS);
  reduce_w<<<(M_ * H_) / 1024, 256, 0, stream>>>(partial, weighted, KS);
  scan<<<SCAN_BLOCKS, 128, 0, stream>>>(weighted, threshold, fre0, tau_mem,
                                        tau_syn, target, lr, out, dpart);
  reduce_d<<<1, 128, 0, stream>>>(dpart, out);
}

// Round 10
// 211.094 us; speedup vs baseline: 1.0556x; 1.0556x over previous
//
#include <hip/hip_runtime.h>
#include <stdint.h>

// Problem constants (fixed by the reference setup)
#define B_ 32
#define I_ 16384
#define H_ 1024
#define T_ 10
#define M_ 320   // T_*B_  (GEMM M dimension, m = t*32 + b)
#define NW 64    // GEMM per-block n-tile width
#define BK 32    // K rows per pipeline stage
#define KS_ 16   // K-split (round 10: halves scattered partial writes vs 32)
#define SCAN_BLOCKS 256   // H_/4

typedef __attribute__((ext_vector_type(8))) short short8;  // 8 bf16 (4 VGPRs)
typedef __attribute__((ext_vector_type(4))) float f32x4;
typedef __attribute__((ext_vector_type(2))) float f32x2;
typedef __attribute__((ext_vector_type(4))) unsigned int u32x4;

// ---------------------------------------------------------------------------
// Kernel 1: pack spikes [B][I][T] f32 -> Sbf [M=T*B][I] bf16 (exact: 0/1)
// ---------------------------------------------------------------------------
__global__ __launch_bounds__(256) void pack_s(const float* __restrict__ spikes,
                                              uint16_t* __restrict__ Sbf) {
  __shared__ __align__(16) uint16_t tile[M_ * 40];  // [m][il], il<32 pad->40
  const int i0 = blockIdx.x * 32;
#pragma unroll
  for (int p = 0; p < 10; p++) {
    int e = p * 256 + threadIdx.x;          // f32x4 index
    int b = e / 80;                          // 80 f32x4 per b-row
    int r = e - b * 80;
    f32x4 val = *(const f32x4*)&spikes[(size_t)b * (I_ * T_) + (size_t)i0 * T_ + r * 4];
#pragma unroll
    for (int j = 0; j < 4; j++) {
      int pos = r * 4 + j;                   // pos = il*10 + t
      int il = pos / 10;
      int t = pos - il * 10;
      float f = (j == 0) ? val.x : (j == 1) ? val.y : (j == 2) ? val.z : val.w;
      union { float f; unsigned int u; } cv; cv.f = f;
      tile[(t * 32 + b) * 40 + il] = (uint16_t)(cv.u >> 16);  // exact for 0/1
    }
  }
  __syncthreads();
#pragma unroll
  for (int p = 0; p < 5; p++) {
    int e = p * 256 + threadIdx.x;
    int m = e >> 2, il8 = e & 3;
    u32x4 w = *(const u32x4*)&tile[m * 40 + il8 * 8];
    *(u32x4*)&Sbf[(size_t)m * I_ + i0 + il8 * 8] = w;
  }
}

// ---------------------------------------------------------------------------
// Kernel 2: GEMM  partial[ks][320][1024] = Sbf * (weight*strength)
// 2-term bf16 split (w = hi + lo); fp32-class accuracy.
//
// ROUND-10: exact round-6 pipeline (best measured: 61 us), with KS 32->16.
// Round-9's counted-vmcnt global_load_lds ring with a verified one-stage
// issue-to-wait lead ran WORSE (71 us) -> concurrency/depth is exonerated
// conclusively; the ~2 TB/s W/S ingest is a DRAM row-activation ceiling of
// the 256-B-segment / 4-KB-stride pattern.  gemm's partial WRITES share
// that pattern (41 MB scattered) -> KS=16 halves them (and halves
// reduce_w traffic).  Grid 16*16 = 256 blocks = 1 block/CU (round-5/6 A/B:
// perf-equal to 2/CU); A k-bands 2 x 640 KB per XCD stay L2-resident.
// Pipeline: reg-staged W/S, raw s_barrier + lgkmcnt-only (loads live
// across barriers), 1-stage lead.  MFMA k-order: ascending 32-k subtiles,
// hi then lo (identical to all prior rounds -> bit-identical output).
// ---------------------------------------------------------------------------
__global__ __launch_bounds__(640, 5) void gemm(const uint16_t* __restrict__ Sbf,
                                               const float* __restrict__ Wg,
                                               const float* __restrict__ Sg,
                                               float* __restrict__ partial,
                                               int kchunk, int KS) {
  __shared__ __align__(16) uint16_t WhiL[2][NW * 40];  // 5.12 KB each buf
  __shared__ __align__(16) uint16_t WloL[2][NW * 40];

  const int ks = blockIdx.x % KS;      // ks fastest: same-ks blocks same XCD
  const int nt = blockIdx.x / KS;
  const int nbase = nt * NW;
  const int tid = threadIdx.x;
  const int lane = tid & 63, wid = tid >> 6;   // wid 0..9
  const int quad = lane >> 4, l15 = lane & 15;

  const int stages = kchunk >> 5;      // BK = 32
  const int kofs = ks * kchunk;

  // A-fragment pointers: lane holds A[m][quad*8 + j] -> 16B contiguous global
  const uint16_t* aptr0 = Sbf + (size_t)(wid * 32 + l15) * I_ + quad * 8;
  const uint16_t* aptr1 = aptr0 + (size_t)16 * I_;

  // W staging mapping (tid < 256): n-column x k-octet (4 octets = 32 k)
  const int wn = tid & 63;             // adjacent lanes -> adjacent columns
  const int wko = (tid >> 6) & 3;      // k-octet within the 32-k stage

  f32x4 acc[2][4];
#pragma unroll
  for (int a = 0; a < 2; a++)
#pragma unroll
    for (int b = 0; b < 4; b++) acc[a][b] = f32x4{0.f, 0.f, 0.f, 0.f};

  u32x4 af[2];                         // current-stage A fragments
  float wpre[8], spre[8];

  // Raw barrier: LDS-write visibility only; vmem loads stay in flight.
#define BAR()                                                               \
  do {                                                                      \
    asm volatile("s_waitcnt lgkmcnt(0)" ::: "memory");                      \
    __builtin_amdgcn_s_barrier();                                           \
    __builtin_amdgcn_sched_barrier(0);                                      \
  } while (0)

  // pack wpre/spre -> hi/lo planes of LDS buffer pn
#define PACK_W(pn)                                                          \
  if (tid < 256) {                                                          \
    unsigned int hw[4], lw[4];                                              \
    _Pragma("unroll")                                                       \
    for (int j2 = 0; j2 < 4; j2++) {                                        \
      unsigned int hh[2], ll[2];                                            \
      _Pragma("unroll")                                                     \
      for (int e = 0; e < 2; e++) {                                         \
        float p = wpre[j2 * 2 + e] * spre[j2 * 2 + e];                      \
        union { float f; unsigned int u; } cv; cv.f = p;                    \
        unsigned int hb = (cv.u + 0x7FFFu + ((cv.u >> 16) & 1u)) >> 16;     \
        union { unsigned int u; float f; } hv; hv.u = hb << 16;             \
        float lo = p - hv.f;                                                \
        union { float f; unsigned int u; } cl; cl.f = lo;                   \
        unsigned int lb = (cl.u + 0x7FFFu + ((cl.u >> 16) & 1u)) >> 16;     \
        hh[e] = hb; ll[e] = lb;                                             \
      }                                                                     \
      hw[j2] = hh[0] | (hh[1] << 16);                                       \
      lw[j2] = ll[0] | (ll[1] << 16);                                       \
    }                                                                       \
    int wofs = wn * 40 + wko * 8;                                           \
    *(u32x4*)&WhiL[pn][wofs] = u32x4{hw[0], hw[1], hw[2], hw[3]};           \
    *(u32x4*)&WloL[pn][wofs] = u32x4{lw[0], lw[1], lw[2], lw[3]};           \
  }

#define LOAD_W(kb)                                                          \
  if (tid < 256) {                                                          \
    _Pragma("unroll")                                                       \
    for (int j = 0; j < 8; j++) {                                           \
      size_t g = (size_t)((kb) + wko * 8 + j) * H_ + nbase + wn;            \
      wpre[j] = Wg[g]; spre[j] = Sg[g];                                     \
    }                                                                       \
  }

#define ISSUE_A(kb)                                                         \
  {                                                                         \
    af[0] = *(const u32x4*)(aptr0 + (kb));                                  \
    af[1] = *(const u32x4*)(aptr1 + (kb));                                  \
  }

#define COMPUTE(pc)                                                         \
  {                                                                         \
    short8 a0 = __builtin_bit_cast(short8, af[0]);                          \
    short8 a1 = __builtin_bit_cast(short8, af[1]);                          \
    _Pragma("unroll")                                                       \
    for (int tn = 0; tn < 4; ++tn) {                                        \
      int n = tn * 16 + l15;                                                \
      short8 bhi = *(const short8*)&WhiL[pc][n * 40 + quad * 8];            \
      short8 blo = *(const short8*)&WloL[pc][n * 40 + quad * 8];            \
      acc[0][tn] = __builtin_amdgcn_mfma_f32_16x16x32_bf16(a0, bhi, acc[0][tn], 0, 0, 0); \
      acc[0][tn] = __builtin_amdgcn_mfma_f32_16x16x32_bf16(a0, blo, acc[0][tn], 0, 0, 0); \
      acc[1][tn] = __builtin_amdgcn_mfma_f32_16x16x32_bf16(a1, bhi, acc[1][tn], 0, 0, 0); \
      acc[1][tn] = __builtin_amdgcn_mfma_f32_16x16x32_bf16(a1, blo, acc[1][tn], 0, 0, 0); \
    }                                                                       \
  }

  // ---- prologue: stage 0 packed, stage 1 loads in flight ----
  LOAD_W(kofs);
  ISSUE_A(kofs);
  PACK_W(0);                           // waits stage-0 W regs, fills buf0
  if (stages > 1) LOAD_W(kofs + BK);   // stage 1: issue only
  BAR();

  // ---- main loop: loads for s+1 are in flight while computing s ----
  for (int s = 0; s < stages; ++s) {
    COMPUTE(s & 1);
    if (s + 1 < stages) {
      ISSUE_A(kofs + (s + 1) * BK);
      PACK_W((s + 1) & 1);             // waits W(s+1) regs; writes other buf
      if (s + 2 < stages) LOAD_W(kofs + (s + 2) * BK);
      BAR();
    }
  }

  // ---- epilogue: C/D layout col=lane&15, row=quad*4+reg ----
#pragma unroll
  for (int tm = 0; tm < 2; tm++)
#pragma unroll
    for (int tn = 0; tn < 4; tn++) {
      int mrow = wid * 32 + tm * 16 + quad * 4;
      int ncol = nbase + tn * 16 + l15;
      float* dst = partial + ((size_t)ks * M_ + mrow) * H_ + ncol;
      dst[0 * H_] = acc[tm][tn].x;
      dst[1 * H_] = acc[tm][tn].y;
      dst[2 * H_] = acc[tm][tn].z;
      dst[3 * H_] = acc[tm][tn].w;
    }
#undef PACK_W
#undef LOAD_W
#undef ISSUE_A
#undef COMPUTE
#undef BAR
}

// ---------------------------------------------------------------------------
// Kernel 3: deterministic reduction of K-split partials -> weighted [320][1024]
// Compile-time unroll for KS=16; single accumulator, ascending k order.
// ---------------------------------------------------------------------------
__global__ __launch_bounds__(256) void reduce_w(const float* __restrict__ partial,
                                                float* __restrict__ weighted,
                                                int KS) {
  int j = (blockIdx.x * 256 + threadIdx.x) * 4;
  f32x4 s = f32x4{0.f, 0.f, 0.f, 0.f};
  if (KS == 16) {
#pragma unroll
    for (int k = 0; k < 16; k++) {
      f32x4 p = *(const f32x4*)&partial[(size_t)k * (M_ * H_) + j];
      s += p;
    }
  } else {
    for (int k = 0; k < KS; k++) {
      f32x4 p = *(const f32x4*)&partial[(size_t)k * (M_ * H_) + j];
      s += p;
    }
  }
  *(f32x4*)&weighted[j] = s;
}

// ---------------------------------------------------------------------------
// Kernel 4: LIF scan (round-5 structure).  One thread per (b,h); win[t]
// preloaded to regs; zero atomics; diag via shfl trees + per-block partials.
// ---------------------------------------------------------------------------
__global__ __launch_bounds__(128) void scan(const float* __restrict__ weighted,
                                            const float* __restrict__ threshold,
                                            const float* __restrict__ fre0,
                                            const float* __restrict__ p_tau_mem,
                                            const float* __restrict__ p_tau_syn,
                                            const float* __restrict__ p_target,
                                            const float* __restrict__ p_lr,
                                            float* __restrict__ out,
                                            float* __restrict__ dpart) {
  const int tid = threadIdx.x;
  const int lane = tid & 63;
  const int wv = tid >> 6;             // wave 0..1
  const int b = lane & 31;             // batch (shfl-reduce dimension)
  const int hg = lane >> 5;            // h within wave (0..1)
  const int h = blockIdx.x * 4 + wv * 2 + hg;

  const float alpha_mem = expf(-0.001f / p_tau_mem[0]);
  const float alpha_syn = expf(-0.001f / p_tau_syn[0]);
  const float target = p_target[0], lr = p_lr[0];

  float win[T_];
#pragma unroll
  for (int t = 0; t < T_; t++)
    win[t] = weighted[(size_t)(t * 32 + b) * H_ + h];

  float fre = fre0[h];
  float thr = threshold[h];
  float v = 0.f, isyn = 0.f;
  float spk[T_], dv[T_], dr[T_], dtt[T_];

#pragma unroll
  for (int t = 0; t < T_; t++) {
    isyn = alpha_syn * isyn + win[t];
    v = alpha_mem * v + isyn;
    float spike = (v >= thr) ? 1.f : 0.f;
    v -= spike * thr;
    spk[t] = spike;
    // spike count over the 32 b-lanes of this h (exact integer sum)
    float r = spike;
    r += __shfl_xor(r, 1);
    r += __shfl_xor(r, 2);
    r += __shfl_xor(r, 4);
    r += __shfl_xor(r, 8);
    r += __shfl_xor(r, 16);
    float rate = r * (1.f / 32.f);
    fre = 0.99f * fre + 0.01f * rate;            // identical in 32 lanes
    thr = thr + lr * (fre - target);
    // diagnostics (wave partials, deterministic trees)
    float vv = v;
#pragma unroll
    for (int off = 1; off <= 32; off <<= 1) vv += __shfl_xor(vv, off);
    float r2 = r + __shfl_xor(r, 32);            // counts: h0+h1 (uniform)
    float t2 = thr + __shfl_xor(thr, 32);        // thr: h0+h1 (uniform)
    dv[t] = vv;                                  // sum v over 64 lanes
    dr[t] = r2 * (1.f / 32.f);                   // rate_h0 + rate_h1 (exact)
    dtt[t] = t2;
  }

  // spike output: 10 contiguous floats at out[b*H*T + h*T]
  {
    float* o = out + (size_t)b * (H_ * T_) + (size_t)h * T_;
#pragma unroll
    for (int p = 0; p < 5; p++)
      *(f32x2*)&o[p * 2] = f32x2{spk[p * 2], spk[p * 2 + 1]};
  }

  // block diag partial: combine the 2 waves via LDS, write 30 floats
  __shared__ float dl[2][30];
  if (lane == 0) {
#pragma unroll
    for (int t = 0; t < T_; t++) {
      dl[wv][t] = dv[t];
      dl[wv][10 + t] = dr[t];
      dl[wv][20 + t] = dtt[t];
    }
  }
  __syncthreads();
  if (tid < 30) dpart[(size_t)blockIdx.x * 30 + tid] = dl[0][tid] + dl[1][tid];
}

// ---------------------------------------------------------------------------
// Kernel 5: reduce the 256x30 diag partials -> out[327680..327709].
// ---------------------------------------------------------------------------
__global__ __launch_bounds__(128) void reduce_d(const float* __restrict__ dpart,
                                                float* __restrict__ out) {
  __shared__ float accl[4][32];
  const int s = threadIdx.x >> 5;      // slice 0..3
  const int c = threadIdx.x & 31;      // counter 0..31 (0..29 valid)
  float sum = 0.f;
  if (c < 30) {
    for (int k = s * 64; k < s * 64 + 64; k++)
      sum += dpart[(size_t)k * 30 + c];
  }
  accl[s][c] = sum;
  __syncthreads();
  if (threadIdx.x < 30) {
    float tot = accl[0][threadIdx.x] + accl[1][threadIdx.x] +
                accl[2][threadIdx.x] + accl[3][threadIdx.x];
    float scale = (threadIdx.x < 10) ? (1.f / 32768.f) : (1.f / 1024.f);
    out[327680 + threadIdx.x] = tot * scale;
  }
}

// ---------------------------------------------------------------------------
extern "C" void kernel_launch(void* const* d_in, const int* in_sizes, int n_in,
                              void* d_out, int out_size, void* d_ws, size_t ws_size,
                              hipStream_t stream) {
  const float* spikes    = (const float*)d_in[0];
  const float* weight    = (const float*)d_in[1];
  const float* strength  = (const float*)d_in[2];
  const float* threshold = (const float*)d_in[3];
  const float* fre0      = (const float*)d_in[4];
  const float* tau_mem   = (const float*)d_in[5];
  const float* tau_syn   = (const float*)d_in[6];
  const float* target    = (const float*)d_in[7];
  const float* lr        = (const float*)d_in[8];
  float* out = (float*)d_out;

  const size_t sbf_bytes = (size_t)M_ * I_ * 2;   // 10.5 MB bf16 A-matrix
  const size_t slice     = (size_t)M_ * H_ * 4;   // 1.31 MB per K-split partial
  const size_t wt_bytes  = (size_t)M_ * H_ * 4;   // weighted
  const size_t dp_bytes  = (size_t)SCAN_BLOCKS * 30 * 4;
  int KS = KS_;                                   // shrink if ws is small
  while (KS > 1 &&
         sbf_bytes + (size_t)KS * slice + wt_bytes + dp_bytes > ws_size)
    KS >>= 1;

  uint16_t* Sbf   = (uint16_t*)d_ws;
  float* partial  = (float*)((char*)d_ws + sbf_bytes);
  float* weighted = (float*)((char*)d_ws + sbf_bytes + (size_t)KS * slice);
  float* dpart    = (float*)((char*)d_ws + sbf_bytes + (size_t)KS * slice + wt_bytes);

  pack_s<<<I_ / 32, 256, 0, stream>>>(spikes, Sbf);
  gemm<<<(H_ / NW) * KS, 640, 0, stream>>>(Sbf, weight, strength, partial,
                                           I_ / KS, KS);
  reduce_w<<<(M_ * H_) / 1024, 256, 0, stream>>>(partial, weighted, KS);
  scan<<<SCAN_BLOCKS, 128, 0, stream>>>(weighted, threshold, fre0, tau_mem,
                                        tau_syn, target, lr, out, dpart);
  reduce_d<<<1, 128, 0, stream>>>(dpart, out);
}